// Round 9
// baseline (272.168 us; speedup 1.0000x reference)
//
#include <hip/hip_runtime.h>
#include <math.h>

#define BB 1024
#define NN 4096
#define HH 32
#define PP 4                  // quarter-batch sub-blocks (both roles)
#define RK1 (NN / PP)         // 1024 rows per quarter
#define QQ 4
#define RQ (NN / QQ)          // 1024 rows per K3a block
#define CHUNK 128             // batches per pipeline chunk (64 MB of ne)
#define NCH (BB / CHUNK)      // 8 chunks
#define K1B (CHUNK * PP)      // 512 K1-role blocks per dispatch
#define K3B (CHUNK * QQ)      // 512 K3a-role blocks per dispatch

// ws layout (floats)
#define WS_PART 0                        // [BB*PP*HH) column-sum partials
#define WS_MS   (BB * PP * HH)           // [BB*QQ*2) per-quarter (max, sum)

// Pipelined kernel. Blocks [0,K1B) stream chunk k1c (column-sum partials);
// blocks [K1B,K1B+K3B) consume chunk k3c = k1c-1 (L3-warm from the previous
// dispatch): fused MLP prelude -> quarter scores -> local softmax -> e-values
// to out, (max,sum) to ws. Negative chunk index disables a role.
__global__ __launch_bounds__(256) void pipe(
    const float* __restrict__ ne,     // [B,N,H]
    const float* __restrict__ mask,   // [B,N]
    const float* __restrict__ times,  // [B]
    const float* __restrict__ W1,     // [H, 2H+1]
    const float* __restrict__ b1,     // [H]
    const float* __restrict__ Wq,     // [H,H]
    const float* __restrict__ Wk,     // [H,H]
    const int*   __restrict__ idxc,   // [B]
    float* __restrict__ ws,
    float* __restrict__ out,          // [B,N]
    float* __restrict__ ws_ms,
    int k1c, int k3c)
{
    __shared__ float smem[RK1 + 160];
    const int tid = threadIdx.x;

    if ((int)blockIdx.x < K1B) {
        // ---------------- K1 role: quarter-batch column-sum partials ----------
        if (k1c < 0) return;
        const int blk = blockIdx.x;
        const int b   = k1c * CHUNK + (blk >> 2);
        const int p   = blk & (PP - 1);
        const int q8  = tid & 7;
        const int r   = tid >> 3;

        float* s_part = smem;   // 1024 floats

        const float* base = ne + (size_t)b * (NN * HH)
                               + (size_t)(p * RK1 + r) * HH + q8 * 4;
        float a0 = 0.f, a1 = 0.f, a2 = 0.f, a3 = 0.f;
        #pragma unroll 8
        for (int i = 0; i < RK1 / 32; ++i) {           // 32 iters
            const float4 v = *reinterpret_cast<const float4*>(base + i * (32 * HH));
            a0 += v.x; a1 += v.y; a2 += v.z; a3 += v.w;
        }
        *reinterpret_cast<float4*>(&s_part[tid * 4]) = make_float4(a0, a1, a2, a3);
        __syncthreads();

        if (tid < HH) {   // deterministic fixed-order reduce
            const int qq = tid >> 2, j = tid & 3;
            float s = 0.f;
            #pragma unroll
            for (int rr = 0; rr < 32; ++rr) s += s_part[(rr * 8 + qq) * 4 + j];
            ws[WS_PART + (b * PP + p) * HH + tid] = s;
        }
        return;
    }

    // ---------------- K3a role: MLP prelude + quarter scores + local softmax --
    if (k3c < 0) return;
    const int j2  = (int)blockIdx.x - K1B;
    const int b   = k3c * CHUNK + (j2 >> 2);
    const int qi  = j2 & (QQ - 1);
    const int q8  = tid & 7;
    const int r   = tid >> 3;            // 0..31

    float* s_scores = smem;              // [RQ)
    float* sh_avg   = smem + RQ;         // [32)
    float* sh_f     = smem + RQ + 32;    // [32)
    float* sh_emb   = smem + RQ + 64;    // [32)
    float* sh_qk    = smem + RQ + 96;    // [32)
    float* red_buf  = smem + RQ + 128;   // [4)
    float* red_sum  = smem + RQ + 136;   // [4)

    // coalesced mask slice for this quarter, loaded early
    const float4 mv = *reinterpret_cast<const float4*>(
        mask + (size_t)b * NN + qi * RQ + tid * 4);

    // prelude: rebuild avg from partials, gather f, tiny MLP -> qk
    if (tid < HH) {
        float s = 0.f;
        #pragma unroll
        for (int p = 0; p < PP; ++p) s += ws[WS_PART + (b * PP + p) * HH + tid];
        sh_avg[tid] = s * (1.0f / (float)NN);
        sh_f[tid]   = ne[(size_t)b * (NN * HH) + (size_t)idxc[b] * HH + tid];
    }
    __syncthreads();
    if (tid < HH) {
        const float t = times[b];
        const float* w = W1 + tid * (2 * HH + 1);
        float e = b1[tid];
        #pragma unroll
        for (int j = 0; j < HH; ++j) e += sh_avg[j] * w[j];
        #pragma unroll
        for (int j = 0; j < HH; ++j) e += sh_f[j] * w[HH + j];
        e += t * w[2 * HH];
        sh_emb[tid] = e;
    }
    __syncthreads();
    if (tid < HH) {  // q = emb @ Wq^T (reuse sh_f)
        const float* w = Wq + tid * HH;
        float qv = 0.f;
        #pragma unroll
        for (int j = 0; j < HH; ++j) qv += sh_emb[j] * w[j];
        sh_f[tid] = qv;
    }
    __syncthreads();
    if (tid < HH) {  // qk[j] = sum_h q[h]*Wk[h,j], scaled 1/sqrt(H)
        float s = 0.f;
        #pragma unroll
        for (int h = 0; h < HH; ++h) s += sh_f[h] * Wk[h * HH + tid];
        sh_qk[tid] = s * 0.17677669529663687f;
    }
    __syncthreads();

    const float kq0 = sh_qk[q8 * 4 + 0];
    const float kq1 = sh_qk[q8 * 4 + 1];
    const float kq2 = sh_qk[q8 * 4 + 2];
    const float kq3 = sh_qk[q8 * 4 + 3];

    const float* base = ne + (size_t)b * (NN * HH)
                           + (size_t)(qi * RQ + r) * HH + q8 * 4;

    #pragma unroll 8
    for (int i = 0; i < RQ / 32; ++i) {                // 32 iters (L3-warm)
        const float4 v = *reinterpret_cast<const float4*>(base + i * (32 * HH));
        float p = v.x * kq0 + v.y * kq1 + v.z * kq2 + v.w * kq3;
        p += __shfl_xor(p, 1);
        p += __shfl_xor(p, 2);
        p += __shfl_xor(p, 4);
        if (q8 == 0) s_scores[r + i * 32] = p;
    }
    __syncthreads();

    // each thread owns 4 consecutive scores; mask, local max
    const float4 s4 = *reinterpret_cast<const float4*>(&s_scores[tid * 4]);
    const float sc0 = s4.x - mv.x * 999999999.0f;
    const float sc1 = s4.y - mv.y * 999999999.0f;
    const float sc2 = s4.z - mv.z * 999999999.0f;
    const float sc3 = s4.w - mv.w * 999999999.0f;

    float lmax = fmaxf(fmaxf(sc0, sc1), fmaxf(sc2, sc3));
    #pragma unroll
    for (int m = 1; m < 64; m <<= 1) lmax = fmaxf(lmax, __shfl_xor(lmax, m));
    if ((tid & 63) == 0) red_buf[tid >> 6] = lmax;
    __syncthreads();
    const float bmax = fmaxf(fmaxf(red_buf[0], red_buf[1]),
                             fmaxf(red_buf[2], red_buf[3]));

    const float e0 = expf(sc0 - bmax);
    const float e1 = expf(sc1 - bmax);
    const float e2 = expf(sc2 - bmax);
    const float e3 = expf(sc3 - bmax);
    float lsum = (e0 + e1) + (e2 + e3);
    #pragma unroll
    for (int m = 1; m < 64; m <<= 1) lsum += __shfl_xor(lsum, m);
    if ((tid & 63) == 0) red_sum[tid >> 6] = lsum;

    *reinterpret_cast<float4*>(out + (size_t)b * NN + qi * RQ + tid * 4) =
        make_float4(e0, e1, e2, e3);

    __syncthreads();
    if (tid == 0) {
        const float bsum = (red_sum[0] + red_sum[1]) + (red_sum[2] + red_sum[3]);
        ws_ms[(b * QQ + qi) * 2 + 0] = bmax;
        ws_ms[(b * QQ + qi) * 2 + 1] = bsum;
    }
}

// ---------------- K3b: combine quarters, rescale in place ----------------
__global__ __launch_bounds__(256) void k3b_rescale(
    const float* __restrict__ ws_ms, float* __restrict__ out)
{
    const int blk = blockIdx.x;
    const int b   = blk >> 2;
    const int qi  = blk & (QQ - 1);
    const int tid = threadIdx.x;

    const float m0 = ws_ms[(b * QQ + 0) * 2 + 0], s0 = ws_ms[(b * QQ + 0) * 2 + 1];
    const float m1 = ws_ms[(b * QQ + 1) * 2 + 0], s1 = ws_ms[(b * QQ + 1) * 2 + 1];
    const float m2 = ws_ms[(b * QQ + 2) * 2 + 0], s2 = ws_ms[(b * QQ + 2) * 2 + 1];
    const float m3 = ws_ms[(b * QQ + 3) * 2 + 0], s3 = ws_ms[(b * QQ + 3) * 2 + 1];

    const float M = fmaxf(fmaxf(m0, m1), fmaxf(m2, m3));
    const float S = s0 * expf(m0 - M) + s1 * expf(m1 - M)
                  + s2 * expf(m2 - M) + s3 * expf(m3 - M);
    const float mq = (qi == 0) ? m0 : (qi == 1) ? m1 : (qi == 2) ? m2 : m3;
    const float scale = expf(mq - M) / S;

    float* p = out + (size_t)b * NN + qi * RQ + tid * 4;
    const float4 v = *reinterpret_cast<const float4*>(p);
    *reinterpret_cast<float4*>(p) =
        make_float4(v.x * scale, v.y * scale, v.z * scale, v.w * scale);
}

extern "C" void kernel_launch(void* const* d_in, const int* in_sizes, int n_in,
                              void* d_out, int out_size, void* d_ws, size_t ws_size,
                              hipStream_t stream) {
    (void)in_sizes; (void)n_in; (void)ws_size; (void)out_size;
    const float* ne    = (const float*)d_in[0];
    const float* mask  = (const float*)d_in[1];
    const float* times = (const float*)d_in[2];
    // d_in[3] = vf, unused (idxc path taken)
    const float* W1    = (const float*)d_in[4];
    const float* b1    = (const float*)d_in[5];
    const float* Wq    = (const float*)d_in[6];
    const float* Wk    = (const float*)d_in[7];
    const int*   idxc  = (const int*)d_in[8];
    float* out = (float*)d_out;
    float* ws  = (float*)d_ws;

    // dispatch d: stream chunk d (K1 role) + consume chunk d-1 (K3a role).
    for (int d = 0; d <= NCH; ++d) {
        const int k1c = (d < NCH) ? d : -1;
        const int k3c = d - 1;
        pipe<<<dim3(K1B + K3B), dim3(256), 0, stream>>>(
            ne, mask, times, W1, b1, Wq, Wk, idxc, ws, out, ws + WS_MS, k1c, k3c);
    }
    k3b_rescale<<<dim3(BB * QQ), dim3(256), 0, stream>>>(ws + WS_MS, out);
}

// Round 11
// 185.637 us; speedup vs baseline: 1.4661x; 1.4661x over previous
//
#include <hip/hip_runtime.h>
#include <math.h>

#define BB 1024
#define NN 4096
#define HH 32
#define PP 4                 // K1 partial blocks per batch
#define RK1 (NN / PP)        // 1024 rows per K1 block

typedef float floatx4 __attribute__((ext_vector_type(4)));

// ws layout (floats)
#define WS_PART 0                    // [BB*PP*HH) column-sum partials
#define WS_QK   (BB * PP * HH)       // [BB*HH) folded query vectors

// ---------------- K1: per-batch column-sum partials (R4 + NT loads) -------
__global__ __launch_bounds__(256) void k1_colsum(
    const float* __restrict__ ne, float* __restrict__ ws)
{
    const int blk = blockIdx.x;
    const int b   = blk >> 2;
    const int p   = blk & (PP - 1);
    const int tid = threadIdx.x;
    const int q8  = tid & 7;     // float4 chunk within row
    const int r   = tid >> 3;    // row offset 0..31

    __shared__ float s_part[256 * 4];

    const float* base = ne + (size_t)b * (NN * HH)
                           + (size_t)(p * RK1 + r) * HH + q8 * 4;
    float a0 = 0.f, a1 = 0.f, a2 = 0.f, a3 = 0.f;
    #pragma unroll 8
    for (int i = 0; i < RK1 / 32; ++i) {               // 32 iters
        const floatx4 v = __builtin_nontemporal_load(
            reinterpret_cast<const floatx4*>(base + i * (32 * HH)));
        a0 += v.x; a1 += v.y; a2 += v.z; a3 += v.w;
    }
    *reinterpret_cast<float4*>(&s_part[tid * 4]) = make_float4(a0, a1, a2, a3);
    __syncthreads();

    // deterministic fixed-order reduce: thread h sums its column's 32 partials
    if (tid < HH) {
        const int q = tid >> 2, j = tid & 3;
        float s = 0.f;
        #pragma unroll
        for (int rr = 0; rr < 32; ++rr) s += s_part[(rr * 8 + q) * 4 + j];
        ws[WS_PART + (b * PP + p) * HH + tid] = s;
    }
}

// ---------------- K2: per-batch tiny MLP -> qk (unchanged from R4) --------
__global__ __launch_bounds__(64) void k2_mlp(
    const float* __restrict__ ne, const float* __restrict__ times,
    const float* __restrict__ W1, const float* __restrict__ b1,
    const float* __restrict__ Wq, const float* __restrict__ Wk,
    const int* __restrict__ idxc, float* __restrict__ ws)
{
    const int b   = blockIdx.x;
    const int tid = threadIdx.x;
    __shared__ float sh_avg[HH], sh_f[HH], sh_emb[HH], sh_q[HH];

    if (tid < HH) {
        float s = 0.f;
        #pragma unroll
        for (int p = 0; p < PP; ++p) s += ws[WS_PART + (b * PP + p) * HH + tid];
        sh_avg[tid] = s * (1.0f / (float)NN);
        sh_f[tid]   = ne[(size_t)b * (NN * HH) + (size_t)idxc[b] * HH + tid];
    }
    __syncthreads();
    if (tid < HH) {
        const float t = times[b];
        const float* w = W1 + tid * (2 * HH + 1);
        float e = b1[tid];
        #pragma unroll
        for (int j = 0; j < HH; ++j) e += sh_avg[j] * w[j];
        #pragma unroll
        for (int j = 0; j < HH; ++j) e += sh_f[j] * w[HH + j];
        e += t * w[2 * HH];
        sh_emb[tid] = e;
    }
    __syncthreads();
    if (tid < HH) {
        const float* w = Wq + tid * HH;
        float qv = 0.f;
        #pragma unroll
        for (int j = 0; j < HH; ++j) qv += sh_emb[j] * w[j];
        sh_q[tid] = qv;
    }
    __syncthreads();
    if (tid < HH) {
        float s = 0.f;
        #pragma unroll
        for (int h = 0; h < HH; ++h) s += sh_q[h] * Wk[h * HH + tid];
        ws[WS_QK + b * HH + tid] = s * 0.17677669529663687f;   // 1/sqrt(32)
    }
}

// ---------------- K3: scores + softmax (R4 + NT loads/stores) -------------
// grid = BB blocks x 256 thr, LDS 16.5 KB -> 8 blocks/CU resident.
__global__ __launch_bounds__(256) void k3_scores(
    const float* __restrict__ ne, const float* __restrict__ mask,
    const float* __restrict__ ws, float* __restrict__ out)
{
    const int b   = blockIdx.x;
    const int tid = threadIdx.x;
    const int q8  = tid & 7;
    const int r   = tid >> 3;    // 0..31

    __shared__ float s_scores[NN];     // 16 KB
    __shared__ float sh_qk[HH];
    __shared__ float red_buf[4];

    if (tid < HH) sh_qk[tid] = ws[WS_QK + b * HH + tid];
    __syncthreads();

    const float kq0 = sh_qk[q8 * 4 + 0];
    const float kq1 = sh_qk[q8 * 4 + 1];
    const float kq2 = sh_qk[q8 * 4 + 2];
    const float kq3 = sh_qk[q8 * 4 + 3];

    const float* base = ne + (size_t)b * (NN * HH) + (size_t)r * HH + q8 * 4;

    // raw dot products into LDS (single-use stream -> NT loads)
    #pragma unroll 8
    for (int i = 0; i < NN / 32; ++i) {               // 128 iters
        const floatx4 v = __builtin_nontemporal_load(
            reinterpret_cast<const floatx4*>(base + i * (32 * HH)));
        float p = v.x * kq0 + v.y * kq1 + v.z * kq2 + v.w * kq3;
        p += __shfl_xor(p, 1);
        p += __shfl_xor(p, 2);
        p += __shfl_xor(p, 4);
        if (q8 == 0) s_scores[r + i * 32] = p;
    }
    __syncthreads();

    // apply mask (coalesced NT float4), block max
    const float* mrow = mask + (size_t)b * NN;
    float lmax = -INFINITY;
    #pragma unroll
    for (int k = 0; k < NN / 1024; ++k) {             // 4 iters, float4 each
        const int n4 = tid + k * 256;                 // float4 index
        const floatx4 mv = __builtin_nontemporal_load(
            reinterpret_cast<const floatx4*>(mrow + n4 * 4));
        float4 sv = *reinterpret_cast<const float4*>(&s_scores[n4 * 4]);
        sv.x -= mv.x * 999999999.0f;
        sv.y -= mv.y * 999999999.0f;
        sv.z -= mv.z * 999999999.0f;
        sv.w -= mv.w * 999999999.0f;
        *reinterpret_cast<float4*>(&s_scores[n4 * 4]) = sv;
        lmax = fmaxf(lmax, fmaxf(fmaxf(sv.x, sv.y), fmaxf(sv.z, sv.w)));
    }
    #pragma unroll
    for (int m = 1; m < 64; m <<= 1) lmax = fmaxf(lmax, __shfl_xor(lmax, m));
    if ((tid & 63) == 0) red_buf[tid >> 6] = lmax;
    __syncthreads();
    const float bmax = fmaxf(fmaxf(red_buf[0], red_buf[1]),
                             fmaxf(red_buf[2], red_buf[3]));

    // exp + sum
    float lsum = 0.f;
    #pragma unroll
    for (int k = 0; k < NN / 256; ++k) {
        const int n = tid + k * 256;
        const float e = expf(s_scores[n] - bmax);
        s_scores[n] = e;
        lsum += e;
    }
    #pragma unroll
    for (int m = 1; m < 64; m <<= 1) lsum += __shfl_xor(lsum, m);
    __syncthreads();                       // red_buf (max) reads done
    if ((tid & 63) == 0) red_buf[tid >> 6] = lsum;
    __syncthreads();
    const float inv = 1.0f / (red_buf[0] + red_buf[1] + red_buf[2] + red_buf[3]);

    float* orow = out + (size_t)b * NN;
    #pragma unroll
    for (int k = 0; k < NN / 1024; ++k) {             // float4 NT stores
        const int n4 = tid + k * 256;
        const float4 ev = *reinterpret_cast<const float4*>(&s_scores[n4 * 4]);
        floatx4 sv;
        sv.x = ev.x * inv; sv.y = ev.y * inv; sv.z = ev.z * inv; sv.w = ev.w * inv;
        __builtin_nontemporal_store(
            sv, reinterpret_cast<floatx4*>(orow + n4 * 4));
    }
}

extern "C" void kernel_launch(void* const* d_in, const int* in_sizes, int n_in,
                              void* d_out, int out_size, void* d_ws, size_t ws_size,
                              hipStream_t stream) {
    (void)in_sizes; (void)n_in; (void)ws_size; (void)out_size;
    const float* ne    = (const float*)d_in[0];
    const float* mask  = (const float*)d_in[1];
    const float* times = (const float*)d_in[2];
    // d_in[3] = vf, unused (idxc path taken)
    const float* W1    = (const float*)d_in[4];
    const float* b1    = (const float*)d_in[5];
    const float* Wq    = (const float*)d_in[6];
    const float* Wk    = (const float*)d_in[7];
    const int*   idxc  = (const int*)d_in[8];
    float* out = (float*)d_out;
    float* ws  = (float*)d_ws;

    k1_colsum<<<dim3(BB * PP), dim3(256), 0, stream>>>(ne, ws);
    k2_mlp<<<dim3(BB), dim3(64), 0, stream>>>(ne, times, W1, b1, Wq, Wk, idxc, ws);
    k3_scores<<<dim3(BB), dim3(256), 0, stream>>>(ne, mask, ws, out);
}

// Round 12
// 183.491 us; speedup vs baseline: 1.4833x; 1.0117x over previous
//
#include <hip/hip_runtime.h>
#include <math.h>

#define BB 1024
#define NN 4096
#define HH 32
#define PP 4                 // K1 partial blocks per batch
#define RK1 (NN / PP)        // 1024 rows per K1 block

typedef float floatx4 __attribute__((ext_vector_type(4)));

// ws layout (floats)
#define WS_PART 0                    // [BB*PP*HH) column-sum partials

// ---------------- K1: per-batch column-sum partials (champion, NT) --------
__global__ __launch_bounds__(256) void k1_colsum(
    const float* __restrict__ ne, float* __restrict__ ws)
{
    const int blk = blockIdx.x;
    const int b   = blk >> 2;
    const int p   = blk & (PP - 1);
    const int tid = threadIdx.x;
    const int q8  = tid & 7;     // float4 chunk within row
    const int r   = tid >> 3;    // row offset 0..31

    __shared__ float s_part[256 * 4];

    const float* base = ne + (size_t)b * (NN * HH)
                           + (size_t)(p * RK1 + r) * HH + q8 * 4;
    float a0 = 0.f, a1 = 0.f, a2 = 0.f, a3 = 0.f;
    #pragma unroll 8
    for (int i = 0; i < RK1 / 32; ++i) {               // 32 iters
        const floatx4 v = __builtin_nontemporal_load(
            reinterpret_cast<const floatx4*>(base + i * (32 * HH)));
        a0 += v.x; a1 += v.y; a2 += v.z; a3 += v.w;
    }
    *reinterpret_cast<float4*>(&s_part[tid * 4]) = make_float4(a0, a1, a2, a3);
    __syncthreads();

    // deterministic fixed-order reduce: thread h sums its column's 32 partials
    if (tid < HH) {
        const int q = tid >> 2, j = tid & 3;
        float s = 0.f;
        #pragma unroll
        for (int rr = 0; rr < 32; ++rr) s += s_part[(rr * 8 + q) * 4 + j];
        ws[WS_PART + (b * PP + p) * HH + tid] = s;
    }
}

// ---------------- K3: fused MLP prelude + scores + softmax (NT) -----------
// grid = BB blocks x 256 thr, LDS 16.6 KB -> 8 blocks/CU resident.
__global__ __launch_bounds__(256) void k3_scores(
    const float* __restrict__ ne, const float* __restrict__ mask,
    const float* __restrict__ times,
    const float* __restrict__ W1, const float* __restrict__ b1,
    const float* __restrict__ Wq, const float* __restrict__ Wk,
    const int* __restrict__ idxc,
    const float* __restrict__ ws, float* __restrict__ out)
{
    const int b   = blockIdx.x;
    const int tid = threadIdx.x;
    const int q8  = tid & 7;
    const int r   = tid >> 3;    // 0..31

    __shared__ float s_scores[NN];     // 16 KB
    __shared__ float sh_avg[HH], sh_f[HH], sh_emb[HH], sh_qk[HH];
    __shared__ float red_buf[4];

    // ---- prelude: rebuild avg from partials, gather f, tiny MLP -> qk ----
    // (validated in R8's K3a at 256 threads; adds ~1% work, hidden by the
    //  7 other resident blocks' streaming)
    if (tid < HH) {
        float s = 0.f;
        #pragma unroll
        for (int p = 0; p < PP; ++p) s += ws[WS_PART + (b * PP + p) * HH + tid];
        sh_avg[tid] = s * (1.0f / (float)NN);
        sh_f[tid]   = ne[(size_t)b * (NN * HH) + (size_t)idxc[b] * HH + tid];
    }
    __syncthreads();
    if (tid < HH) {
        const float t = times[b];
        const float* w = W1 + tid * (2 * HH + 1);
        float e = b1[tid];
        #pragma unroll
        for (int j = 0; j < HH; ++j) e += sh_avg[j] * w[j];
        #pragma unroll
        for (int j = 0; j < HH; ++j) e += sh_f[j] * w[HH + j];
        e += t * w[2 * HH];
        sh_emb[tid] = e;
    }
    __syncthreads();
    if (tid < HH) {  // q = emb @ Wq^T (reuse sh_f)
        const float* w = Wq + tid * HH;
        float qv = 0.f;
        #pragma unroll
        for (int j = 0; j < HH; ++j) qv += sh_emb[j] * w[j];
        sh_f[tid] = qv;
    }
    __syncthreads();
    if (tid < HH) {  // qk[j] = sum_h q[h]*Wk[h,j], scaled 1/sqrt(H)
        float s = 0.f;
        #pragma unroll
        for (int h = 0; h < HH; ++h) s += sh_f[h] * Wk[h * HH + tid];
        sh_qk[tid] = s * 0.17677669529663687f;
    }
    __syncthreads();

    const float kq0 = sh_qk[q8 * 4 + 0];
    const float kq1 = sh_qk[q8 * 4 + 1];
    const float kq2 = sh_qk[q8 * 4 + 2];
    const float kq3 = sh_qk[q8 * 4 + 3];

    const float* base = ne + (size_t)b * (NN * HH) + (size_t)r * HH + q8 * 4;

    // ---- raw dot products into LDS (single-use stream -> NT loads) ----
    #pragma unroll 8
    for (int i = 0; i < NN / 32; ++i) {               // 128 iters
        const floatx4 v = __builtin_nontemporal_load(
            reinterpret_cast<const floatx4*>(base + i * (32 * HH)));
        float p = v.x * kq0 + v.y * kq1 + v.z * kq2 + v.w * kq3;
        p += __shfl_xor(p, 1);
        p += __shfl_xor(p, 2);
        p += __shfl_xor(p, 4);
        if (q8 == 0) s_scores[r + i * 32] = p;
    }
    __syncthreads();

    // ---- apply mask (coalesced NT float4), block max ----
    const float* mrow = mask + (size_t)b * NN;
    float lmax = -INFINITY;
    #pragma unroll
    for (int k = 0; k < NN / 1024; ++k) {             // 4 iters, float4 each
        const int n4 = tid + k * 256;                 // float4 index
        const floatx4 mv = __builtin_nontemporal_load(
            reinterpret_cast<const floatx4*>(mrow + n4 * 4));
        float4 sv = *reinterpret_cast<const float4*>(&s_scores[n4 * 4]);
        sv.x -= mv.x * 999999999.0f;
        sv.y -= mv.y * 999999999.0f;
        sv.z -= mv.z * 999999999.0f;
        sv.w -= mv.w * 999999999.0f;
        *reinterpret_cast<float4*>(&s_scores[n4 * 4]) = sv;
        lmax = fmaxf(lmax, fmaxf(fmaxf(sv.x, sv.y), fmaxf(sv.z, sv.w)));
    }
    #pragma unroll
    for (int m = 1; m < 64; m <<= 1) lmax = fmaxf(lmax, __shfl_xor(lmax, m));
    if ((tid & 63) == 0) red_buf[tid >> 6] = lmax;
    __syncthreads();
    const float bmax = fmaxf(fmaxf(red_buf[0], red_buf[1]),
                             fmaxf(red_buf[2], red_buf[3]));

    // ---- exp + sum ----
    float lsum = 0.f;
    #pragma unroll
    for (int k = 0; k < NN / 256; ++k) {
        const int n = tid + k * 256;
        const float e = expf(s_scores[n] - bmax);
        s_scores[n] = e;
        lsum += e;
    }
    #pragma unroll
    for (int m = 1; m < 64; m <<= 1) lsum += __shfl_xor(lsum, m);
    __syncthreads();                       // red_buf (max) reads done
    if ((tid & 63) == 0) red_buf[tid >> 6] = lsum;
    __syncthreads();
    const float inv = 1.0f / (red_buf[0] + red_buf[1] + red_buf[2] + red_buf[3]);

    float* orow = out + (size_t)b * NN;
    #pragma unroll
    for (int k = 0; k < NN / 1024; ++k) {             // float4 NT stores
        const int n4 = tid + k * 256;
        const float4 ev = *reinterpret_cast<const float4*>(&s_scores[n4 * 4]);
        floatx4 sv;
        sv.x = ev.x * inv; sv.y = ev.y * inv; sv.z = ev.z * inv; sv.w = ev.w * inv;
        __builtin_nontemporal_store(
            sv, reinterpret_cast<floatx4*>(orow + n4 * 4));
    }
}

extern "C" void kernel_launch(void* const* d_in, const int* in_sizes, int n_in,
                              void* d_out, int out_size, void* d_ws, size_t ws_size,
                              hipStream_t stream) {
    (void)in_sizes; (void)n_in; (void)ws_size; (void)out_size;
    const float* ne    = (const float*)d_in[0];
    const float* mask  = (const float*)d_in[1];
    const float* times = (const float*)d_in[2];
    // d_in[3] = vf, unused (idxc path taken)
    const float* W1    = (const float*)d_in[4];
    const float* b1    = (const float*)d_in[5];
    const float* Wq    = (const float*)d_in[6];
    const float* Wk    = (const float*)d_in[7];
    const int*   idxc  = (const int*)d_in[8];
    float* out = (float*)d_out;
    float* ws  = (float*)d_ws;

    k1_colsum<<<dim3(BB * PP), dim3(256), 0, stream>>>(ne, ws);
    k3_scores<<<dim3(BB), dim3(256), 0, stream>>>(
        ne, mask, times, W1, b1, Wq, Wk, idxc, ws, out);
}